// Round 2
// baseline (421.605 us; speedup 1.0000x reference)
//
#include <hip/hip_runtime.h>

// Pipeline (4 kernels):
//   k_prep_w     : attn_W -> Wa bf16 (208 rows, 200..207 zero), fc_W -> Wf bf16 (remapped, gap zero)
//   k_gemm1_attn : reads f32 images/tag, converts to bf16 (writes Abf img/tag cols),
//                  region GEMM with Wa direct-from-L2-to-registers, fused attention,
//                  writes boxfeat into Abf cols 2048..2303
//   k_gemm2      : dout = Abf @ Wf^T, 144x128 tile, grid 512 = 2 blocks/CU exact,
//                  global_load_lds + XOR swizzle, XCD-aware N-panel mapping
//   k_norm       : bias + L2 normalize in place
// Workspace (64,086,016 B): Abf[9216][3072] | Wf[1024][3072] | Wa[208][2816]

#define M_TOT 9216
#define K1    2816
#define K2    3072
#define ES    1024

typedef __attribute__((ext_vector_type(8))) short bf16x8;
typedef __attribute__((ext_vector_type(4))) float floatx4;

static __device__ __forceinline__ unsigned short f2bf(float f) {
    unsigned int u = __float_as_uint(f);
    u += 0x7fffu + ((u >> 16) & 1u);   // RNE
    return (unsigned short)(u >> 16);
}

static __device__ __forceinline__ uint4 pack8(const float4 f0, const float4 f1) {
    uint4 pk;
    pk.x = (unsigned)f2bf(f0.x) | ((unsigned)f2bf(f0.y) << 16);
    pk.y = (unsigned)f2bf(f0.z) | ((unsigned)f2bf(f0.w) << 16);
    pk.z = (unsigned)f2bf(f1.x) | ((unsigned)f2bf(f1.y) << 16);
    pk.w = (unsigned)f2bf(f1.z) | ((unsigned)f2bf(f1.w) << 16);
    return pk;
}

static __device__ __forceinline__ void cvt8(const float* __restrict__ g,
                                            unsigned short* __restrict__ d) {
    *(uint4*)d = pack8(*(const float4*)g, *(const float4*)(g + 4));
}

// async global->LDS, 16 B per lane; LDS dest must be wave-uniform base (+lane*16)
static __device__ __forceinline__ void gl16(const void* g, const void* l) {
    __builtin_amdgcn_global_load_lds(
        (const __attribute__((address_space(1))) unsigned int*)g,
        (__attribute__((address_space(3))) unsigned int*)(unsigned int)(unsigned long long)l,
        16, 0, 0);
}

// ============ prep weights: Wa + Wf (bf16, padded/remapped) ============
// grid 1822 x 256 covers 1024*384 Wf chunks then 208*352 Wa chunks.
__global__ __launch_bounds__(256) void k_prep_w(
    const float* __restrict__ attn_W,   // [200][2816]
    const float* __restrict__ fc_W,     // [1024][3016]
    unsigned short* __restrict__ Wa,    // [208][2816]
    unsigned short* __restrict__ Wf)    // [1024][3072]
{
    const int u = blockIdx.x * 256 + threadIdx.x;
    const int NWF = 1024 * 384;
    uint4 z; z.x = z.y = z.z = z.w = 0u;
    if (u < NWF) {
        const int r = u / 384;
        const int dc = (u - r * 384) * 8;
        unsigned short* d = Wf + (long)r * K2 + dc;
        if (dc < 2248)      cvt8(fc_W + (long)r * 3016 + dc, d);        // img+box cols
        else if (dc < 2304) *(uint4*)d = z;                             // zero gap
        else                cvt8(fc_W + (long)r * 3016 + (dc - 56), d); // tag cols
    } else {
        const int v = u - NWF;
        if (v < 208 * 352) {
            const int r = v / 352;
            const int c = (v - r * 352) * 8;
            if (r < 200) cvt8(attn_W + (long)r * K1 + c, Wa + (long)r * K1 + c);
            else         *(uint4*)(Wa + (long)r * K1 + c) = z;
        }
    }
}

// ============ GEMM1 (region = imgtag @ Wa^T) + prep_a fusion + attention ============
// grid 576 x 384 threads (6 waves). Block: 16 rows x 208 cols.
// A: f32 load (prefetched across barrier) -> cvt -> swizzled LDS + Abf global write.
// B: Wa rows loaded straight from L2 into registers (no LDS, no staging barrier).
__global__ __launch_bounds__(384, 3) void k_gemm1_attn(
    const float* __restrict__ images,         // [9216][2048]
    const float* __restrict__ tag,            // [9216][768]
    const unsigned short* __restrict__ Wa,    // [208][2816] bf16
    const float* __restrict__ boxes,          // [9216][30]
    const float* __restrict__ pos_emb,        // [257][200]
    unsigned short* __restrict__ Abf)         // [9216][3072] bf16 (all cols written here)
{
    __shared__ __align__(16) float ldsR[16][212];            // 13,568 B; front 2 KB doubles as ldsA
    unsigned short* ldsA = (unsigned short*)&ldsR[0][0];     // [16][64] bf16, XOR-swizzled chunks

    const int t = threadIdx.x;
    const int lane = t & 63;
    const int w = t >> 6;                 // 0..5
    const int quad = lane >> 4;
    const int ln15 = lane & 15;
    const int x7 = ln15 & 15 & 7;
    const int m0 = blockIdx.x * 16;
    const int nj = (w == 0) ? 3 : 2;      // j = w + jj*6 -> {0,6,12},{1,7},..,{5,11}

    // staging role: waves 4,5 (128 threads) convert the 16x64 A tile
    const bool stager = (t >= 256);
    const int sr = (t - 256) >> 3;        // 0..15
    const int sc = (t - 256) & 7;         // 0..7

    floatx4 acc[3] = {};
    float4 v0, v1;

    // prologue: prefetch f32 A tile for kt=0
    if (stager) {
        const float* src = images + (long)(m0 + sr) * 2048 + sc * 8;
        v0 = *(const float4*)src;
        v1 = *(const float4*)(src + 4);
    }

    for (int kt = 0; kt < 44; ++kt) {
        const int kb = kt * 64;
        if (stager) {
            const uint4 pk = pack8(v0, v1);
            *(uint4*)&ldsA[sr * 64 + ((sc ^ (sr & 7)) << 3)] = pk;     // swizzled LDS
            const int acol = kb + ((kb >= 2048) ? 256 : 0);            // skip boxfeat gap
            *(uint4*)(Abf + (long)(m0 + sr) * K2 + acol + sc * 8) = pk; // feed gemm2
        }
        __syncthreads();
        if (stager && kt < 43) {          // prefetch next tile; latency hides under MFMA
            const int kn = kb + 64;
            const float* src = (kn < 2048)
                ? images + (long)(m0 + sr) * 2048 + kn + sc * 8
                : tag + (long)(m0 + sr) * 768 + (kn - 2048) + sc * 8;
            v0 = *(const float4*)src;
            v1 = *(const float4*)(src + 4);
        }
#pragma unroll
        for (int s = 0; s < 2; ++s) {
            const int g = s * 4 + quad;
            const bf16x8 a = *(const bf16x8*)&ldsA[ln15 * 64 + ((g ^ x7) << 3)];
#pragma unroll
            for (int jj = 0; jj < 3; ++jj) {
                if (jj < nj) {
                    const int j = w + jj * 6;
                    const bf16x8 b = *(const bf16x8*)(Wa + (long)(j * 16 + ln15) * K1 + kb + g * 8);
                    acc[jj] = __builtin_amdgcn_mfma_f32_16x16x32_bf16(a, b, acc[jj], 0, 0, 0);
                }
            }
        }
        __syncthreads();
    }

    // acc -> region LDS f32 [16][212] (C layout: row = quad*4+reg, col = j*16+ln15)
#pragma unroll
    for (int jj = 0; jj < 3; ++jj) {
        if (jj < nj) {
            const int j = w + jj * 6;
#pragma unroll
            for (int r = 0; r < 4; ++r)
                ldsR[quad * 4 + r][j * 16 + ln15] = acc[jj][r];
        }
    }
    __syncthreads();

    // attention: wave w handles rows w, w+6, w+12 (<16)
    for (int rr = 0; rr < 3; ++rr) {
        const int ml = w + rr * 6;
        if (ml >= 16) break;
        const int m = m0 + ml;
        float rv[4];
#pragma unroll
        for (int c = 0; c < 4; ++c) {
            const int e = lane + c * 64;
            rv[c] = (e < 200) ? ldsR[ml][e] : 0.0f;
        }
        const float* bx = boxes + (long)m * 30;
        int idx[15]; float bw[15], sc_[15];
#pragma unroll
        for (int k = 0; k < 15; ++k) {
            int ii = (int)bx[k];
            idx[k] = (ii < 0) ? 0 : (ii > 256 ? 256 : ii);
            bw[k] = bx[15 + k];
        }
#pragma unroll
        for (int k = 0; k < 15; ++k) {
            const float* em = pos_emb + (long)idx[k] * 200;
            float p = 0.0f;
#pragma unroll
            for (int c = 0; c < 4; ++c) {
                const int e = lane + c * 64;
                if (e < 200) p += rv[c] * em[e];
            }
            for (int off = 32; off; off >>= 1) p += __shfl_xor(p, off, 64);
            sc_[k] = p;
        }
        float mx = -1e30f;
#pragma unroll
        for (int k = 0; k < 15; ++k) { sc_[k] = tanhf(sc_[k]); mx = fmaxf(mx, sc_[k]); }
        float Z = 0.0f, den = 0.0f, pk[15];
#pragma unroll
        for (int k = 0; k < 15; ++k) { pk[k] = __expf(sc_[k] - mx); Z += pk[k]; }
#pragma unroll
        for (int k = 0; k < 15; ++k) { pk[k] *= bw[k]; den += pk[k]; }
        den += 1e-6f * Z;                 // softmax*w / (sum + eps) exactly
        const float inv = 1.0f / den;
        unsigned short* bo = Abf + (long)m * K2 + 2048;
#pragma unroll
        for (int c = 0; c < 4; ++c) {
            const int e = lane + c * 64;
            float o = 0.0f;
            if (e < 200) {
#pragma unroll
                for (int k = 0; k < 15; ++k) o += pk[k] * pos_emb[(long)idx[k] * 200 + e];
                o *= inv;
            }
            bo[e] = f2bf(o);              // cols 200..255 get exact 0
        }
    }
}

// ============ GEMM2: dout(f32) = Abf[9216][3072] @ Wf^T ============
// 144x128 tile, 384 threads (2x3 wave grid), grid 512 = exactly 2 blocks/CU.
// nx = bid&7 keeps one Wf N-panel (786 KB) hot per XCD L2.
__global__ __launch_bounds__(384, 3) void k_gemm2(
    const unsigned short* __restrict__ Abf,
    const unsigned short* __restrict__ Wf,
    float* __restrict__ dout)
{
    __shared__ __align__(16) unsigned short ldsA[144 * 64];   // 18,432 B
    __shared__ __align__(16) unsigned short ldsB[128 * 64];   // 16,384 B
    const int t = threadIdx.x;
    const int lane = t & 63;
    const int w = t >> 6;                 // 0..5
    const int quad = lane >> 4;
    const int ln15 = lane & 15;
    const int x7 = ln15 & 7;
    const int nx = blockIdx.x & 7;        // 8 XCDs round-robin consecutive bids
    const int mx = blockIdx.x >> 3;       // 0..63
    const int m0 = mx * 144;
    const int n0 = nx * 128;
    const int lrow = lane >> 3;
    const int schunk = (lane & 7) ^ lrow; // inverse-swizzled source chunk
    const int wm = (w % 3) * 48;
    const int wn = (w / 3) * 64;

    floatx4 acc[3][4] = {};

    for (int kt = 0; kt < 48; ++kt) {
        const int kb = kt * 64;
#pragma unroll
        for (int i = 0; i < 6; ++i) {
            const int u = w + i * 6;      // 34 units: 0..17 = A (144 rows), 18..33 = B (128 rows)
            if (u < 18) {
                gl16(Abf + (long)(m0 + u * 8 + lrow) * K2 + kb + schunk * 8, ldsA + u * 512);
            } else if (u < 34) {
                gl16(Wf + (long)(n0 + (u - 18) * 8 + lrow) * K2 + kb + schunk * 8,
                     ldsB + (u - 18) * 512);
            }
        }
        __syncthreads();
#pragma unroll
        for (int s = 0; s < 2; ++s) {
            const int g = s * 4 + quad;
            const int co = (g ^ x7) << 3;
            bf16x8 a[3], b[4];
#pragma unroll
            for (int i = 0; i < 3; ++i)
                a[i] = *(const bf16x8*)&ldsA[(wm + i * 16 + ln15) * 64 + co];
#pragma unroll
            for (int j = 0; j < 4; ++j)
                b[j] = *(const bf16x8*)&ldsB[(wn + j * 16 + ln15) * 64 + co];
#pragma unroll
            for (int i = 0; i < 3; ++i)
#pragma unroll
                for (int j = 0; j < 4; ++j)
                    acc[i][j] = __builtin_amdgcn_mfma_f32_16x16x32_bf16(a[i], b[j], acc[i][j], 0, 0, 0);
        }
        __syncthreads();
    }
#pragma unroll
    for (int i = 0; i < 3; ++i)
#pragma unroll
        for (int j = 0; j < 4; ++j) {
            const int row = m0 + wm + i * 16 + quad * 4;
            const int col = n0 + wn + j * 16 + ln15;
#pragma unroll
            for (int r = 0; r < 4; ++r)
                dout[(long)(row + r) * ES + col] = acc[i][j][r];
        }
}

// ============ bias + L2 normalize, IN-PLACE in d_out (f32) ============
__global__ __launch_bounds__(256) void k_norm(
    float* __restrict__ dout,
    const float* __restrict__ bias)
{
    __shared__ float red[4];
    const int m = blockIdx.x;
    const int t = threadIdx.x;
    float* f = dout + (long)m * ES + t * 4;
    float4 v = *(const float4*)f;
    const float4 bs = *(const float4*)(bias + t * 4);
    v.x += bs.x; v.y += bs.y; v.z += bs.z; v.w += bs.w;
    float ss = v.x * v.x + v.y * v.y + v.z * v.z + v.w * v.w;
    for (int off = 32; off; off >>= 1) ss += __shfl_xor(ss, off, 64);
    if ((t & 63) == 0) red[t >> 6] = ss;
    __syncthreads();
    const float total = red[0] + red[1] + red[2] + red[3];
    const float inv = 1.0f / (sqrtf(total) + 1e-8f);
    float4 o;
    o.x = v.x * inv; o.y = v.y * inv; o.z = v.z * inv; o.w = v.w * inv;
    *(float4*)f = o;
}

// ============ launch ============
extern "C" void kernel_launch(void* const* d_in, const int* in_sizes, int n_in,
                              void* d_out, int out_size, void* d_ws, size_t ws_size,
                              hipStream_t stream) {
    const float* images  = (const float*)d_in[0];
    const float* tag     = (const float*)d_in[1];
    const float* boxes   = (const float*)d_in[2];
    const float* pos_emb = (const float*)d_in[3];
    const float* attn_W  = (const float*)d_in[4];
    const float* fc_W    = (const float*)d_in[5];
    const float* fc_b    = (const float*)d_in[6];
    float* out = (float*)d_out;

    unsigned short* Abf = (unsigned short*)d_ws;            // 56,623,104 B
    unsigned short* Wf  = Abf + (size_t)M_TOT * K2;         //  6,291,456 B
    unsigned short* Wa  = Wf  + (size_t)ES * K2;            //  1,171,456 B
    // total workspace: 64,086,016 B

    k_prep_w    <<<1822, 256, 0, stream>>>(attn_W, fc_W, Wa, Wf);
    k_gemm1_attn<<<576, 384, 0, stream>>>(images, tag, Wa, boxes, pos_emb, Abf);
    k_gemm2     <<<512, 384, 0, stream>>>(Abf, Wf, out);
    k_norm      <<<M_TOT, 256, 0, stream>>>(out, fc_b);
}

// Round 3
// 397.946 us; speedup vs baseline: 1.0595x; 1.0595x over previous
//
#include <hip/hip_runtime.h>

// Pipeline (4 kernels):
//   k_prep_w     : attn_W -> Wa bf16 (rows 200..207 zero), fc_W -> Wf bf16 (remapped, gap zero)
//   k_gemm1_attn : fused prep_a + GEMM1 + attention. A: f32 images/tag -> bf16 (reg-prefetch,
//                  writes Abf img/tag cols as side effect). B: Wa staged to LDS via
//                  global_load_lds, DOUBLE-BUFFERED (1 barrier/K-step). Boxfeat -> Abf cols 2048..
//   k_gemm2      : dout = Abf @ Wf^T, 144x128 tile, grid 512 = 2 blocks/CU exact,
//                  double-buffered global_load_lds staging, XCD-aware N-panel mapping
//   k_norm       : bias + L2 normalize in place
// Workspace (64,086,016 B): Abf[9216][3072] | Wf[1024][3072] | Wa[208][2816]

#define M_TOT 9216
#define K1    2816
#define K2    3072
#define ES    1024

typedef __attribute__((ext_vector_type(8))) short bf16x8;
typedef __attribute__((ext_vector_type(4))) float floatx4;

static __device__ __forceinline__ unsigned short f2bf(float f) {
    unsigned int u = __float_as_uint(f);
    u += 0x7fffu + ((u >> 16) & 1u);   // RNE
    return (unsigned short)(u >> 16);
}

static __device__ __forceinline__ uint4 pack8(const float4 f0, const float4 f1) {
    uint4 pk;
    pk.x = (unsigned)f2bf(f0.x) | ((unsigned)f2bf(f0.y) << 16);
    pk.y = (unsigned)f2bf(f0.z) | ((unsigned)f2bf(f0.w) << 16);
    pk.z = (unsigned)f2bf(f1.x) | ((unsigned)f2bf(f1.y) << 16);
    pk.w = (unsigned)f2bf(f1.z) | ((unsigned)f2bf(f1.w) << 16);
    return pk;
}

static __device__ __forceinline__ void cvt8(const float* __restrict__ g,
                                            unsigned short* __restrict__ d) {
    *(uint4*)d = pack8(*(const float4*)g, *(const float4*)(g + 4));
}

// async global->LDS, 16 B per lane; LDS dest must be wave-uniform base (+lane*16)
static __device__ __forceinline__ void gl16(const void* g, const void* l) {
    __builtin_amdgcn_global_load_lds(
        (const __attribute__((address_space(1))) unsigned int*)g,
        (__attribute__((address_space(3))) unsigned int*)(unsigned int)(unsigned long long)l,
        16, 0, 0);
}

// ============ prep weights: Wa + Wf (bf16, padded/remapped) ============
__global__ __launch_bounds__(256) void k_prep_w(
    const float* __restrict__ attn_W,   // [200][2816]
    const float* __restrict__ fc_W,     // [1024][3016]
    unsigned short* __restrict__ Wa,    // [208][2816]
    unsigned short* __restrict__ Wf)    // [1024][3072]
{
    const int u = blockIdx.x * 256 + threadIdx.x;
    const int NWF = 1024 * 384;
    uint4 z; z.x = z.y = z.z = z.w = 0u;
    if (u < NWF) {
        const int r = u / 384;
        const int dc = (u - r * 384) * 8;
        unsigned short* d = Wf + (long)r * K2 + dc;
        if (dc < 2248)      cvt8(fc_W + (long)r * 3016 + dc, d);        // img+box cols
        else if (dc < 2304) *(uint4*)d = z;                             // zero gap
        else                cvt8(fc_W + (long)r * 3016 + (dc - 56), d); // tag cols
    } else {
        const int v = u - NWF;
        if (v < 208 * 352) {
            const int r = v / 352;
            const int c = (v - r * 352) * 8;
            if (r < 200) cvt8(attn_W + (long)r * K1 + c, Wa + (long)r * K1 + c);
            else         *(uint4*)(Wa + (long)r * K1 + c) = z;
        }
    }
}

// ============ GEMM1 (region = imgtag @ Wa^T) + prep_a fusion + attention ============
// grid 576 x 384 threads (6 waves). Block: 16 rows x 208 cols.
// Double-buffered: stage(t+1) issued before MFMA(t); ONE barrier per K-step.
// A: f32 load (reg-prefetch) -> pack -> swizzled LDS + Abf global write.
// B: Wa -> LDS via global_load_lds (26 units x 1 KB), XOR chunk swizzle.
__global__ __launch_bounds__(384, 3) void k_gemm1_attn(
    const float* __restrict__ images,         // [9216][2048]
    const float* __restrict__ tag,            // [9216][768]
    const unsigned short* __restrict__ Wa,    // [208][2816] bf16
    const float* __restrict__ boxes,          // [9216][30]
    const float* __restrict__ pos_emb,        // [257][200]
    unsigned short* __restrict__ Abf)         // [9216][3072] bf16 (all cols written here)
{
    // [2][208][64] B double-buffer | [2][16][64] A double-buffer ; ldsR f32 aliases front
    __shared__ __align__(16) unsigned short shm[2 * 13312 + 2 * 1024];   // 57,344 B
    unsigned short* bufB = shm;                  // + cur*13312
    unsigned short* bufA = shm + 2 * 13312;      // + cur*1024
    float* ldsR = (float*)shm;                   // [16][212], reused after K-loop

    const int t = threadIdx.x;
    const int lane = t & 63;
    const int w = t >> 6;                 // 0..5
    const int quad = lane >> 4;
    const int ln15 = lane & 15;
    const int x7 = ln15 & 7;
    const int m0 = blockIdx.x * 16;
    const int lrow = lane >> 3;           // row within 8-row unit
    const int schunk = (lane & 7) ^ lrow; // inverse-swizzled source chunk
    const int nj = (w == 0) ? 3 : 2;      // j = w + jj*6

    // staging role: waves 4,5 (128 threads) convert the 16x64 A tile
    const bool stager = (t >= 256);
    const int sr = (t - 256) >> 3;        // 0..15
    const int sc = (t - 256) & 7;         // 0..7
    const int aslot = sr * 64 + ((sc ^ (sr & 7)) << 3);

    floatx4 acc[3] = {};
    float4 v0, v1;

    // ---- prologue: A tile 0 -> bufA[0] (+Abf), prefetch A tile 1; B tile 0 -> bufB[0]
    if (stager) {
        const float* src = images + (long)(m0 + sr) * 2048 + sc * 8;
        const uint4 pk = pack8(*(const float4*)src, *(const float4*)(src + 4));
        *(uint4*)&bufA[aslot] = pk;
        *(uint4*)(Abf + (long)(m0 + sr) * K2 + sc * 8) = pk;
        const float* s1 = images + (long)(m0 + sr) * 2048 + 64 + sc * 8;
        v0 = *(const float4*)s1;
        v1 = *(const float4*)(s1 + 4);
    }
#pragma unroll
    for (int i = 0; i < 5; ++i) {
        const int u = w + i * 6;
        if (u < 26) gl16(Wa + (long)(u * 8 + lrow) * K1 + schunk * 8, bufB + u * 512);
    }
    __syncthreads();

    int cur = 0;
    for (int kt = 0; kt < 44; ++kt) {
        const int kb = kt * 64;
        if (kt < 43) {
            const int kbn = kb + 64;
            if (stager) {               // pack tile kt+1 -> bufA[cur^1] (+Abf)
                const uint4 pk = pack8(v0, v1);
                *(uint4*)&bufA[(cur ^ 1) * 1024 + aslot] = pk;
                const int acol = kbn + ((kbn >= 2048) ? 256 : 0);
                *(uint4*)(Abf + (long)(m0 + sr) * K2 + acol + sc * 8) = pk;
                if (kt < 42) {          // prefetch f32 tile kt+2
                    const int kn = kbn + 64;
                    const float* src = (kn < 2048)
                        ? images + (long)(m0 + sr) * 2048 + kn + sc * 8
                        : tag + (long)(m0 + sr) * 768 + (kn - 2048) + sc * 8;
                    v0 = *(const float4*)src;
                    v1 = *(const float4*)(src + 4);
                }
            }
#pragma unroll
            for (int i = 0; i < 5; ++i) {   // B tile kt+1 -> bufB[cur^1]
                const int u = w + i * 6;
                if (u < 26)
                    gl16(Wa + (long)(u * 8 + lrow) * K1 + kbn + schunk * 8,
                         bufB + (cur ^ 1) * 13312 + u * 512);
            }
        }
        // MFMA on buf[cur]
#pragma unroll
        for (int s = 0; s < 2; ++s) {
            const int g = s * 4 + quad;
            const int co = (g ^ x7) << 3;
            const bf16x8 a = *(const bf16x8*)&bufA[cur * 1024 + ln15 * 64 + co];
#pragma unroll
            for (int jj = 0; jj < 3; ++jj) {
                if (jj < nj) {
                    const int j = w + jj * 6;
                    const bf16x8 b = *(const bf16x8*)&bufB[cur * 13312 + (j * 16 + ln15) * 64 + co];
                    acc[jj] = __builtin_amdgcn_mfma_f32_16x16x32_bf16(a, b, acc[jj], 0, 0, 0);
                }
            }
        }
        __syncthreads();   // drains stage(kt+1) + separates buffer reuse
        cur ^= 1;
    }

    // acc -> region LDS f32 [16][212] (C layout: row = quad*4+reg, col = j*16+ln15)
#pragma unroll
    for (int jj = 0; jj < 3; ++jj) {
        if (jj < nj) {
            const int j = w + jj * 6;
#pragma unroll
            for (int r = 0; r < 4; ++r)
                ldsR[(quad * 4 + r) * 212 + j * 16 + ln15] = acc[jj][r];
        }
    }
    __syncthreads();

    // attention: wave w handles rows w, w+6, w+12 (<16)
    for (int rr = 0; rr < 3; ++rr) {
        const int ml = w + rr * 6;
        if (ml >= 16) break;
        const int m = m0 + ml;
        float rv[4];
#pragma unroll
        for (int c = 0; c < 4; ++c) {
            const int e = lane + c * 64;
            rv[c] = (e < 200) ? ldsR[ml * 212 + e] : 0.0f;
        }
        const float* bx = boxes + (long)m * 30;
        int idx[15]; float bw[15], sc_[15];
#pragma unroll
        for (int k = 0; k < 15; ++k) {
            int ii = (int)bx[k];
            idx[k] = (ii < 0) ? 0 : (ii > 256 ? 256 : ii);
            bw[k] = bx[15 + k];
        }
#pragma unroll
        for (int k = 0; k < 15; ++k) {
            const float* em = pos_emb + (long)idx[k] * 200;
            float p = 0.0f;
#pragma unroll
            for (int c = 0; c < 4; ++c) {
                const int e = lane + c * 64;
                if (e < 200) p += rv[c] * em[e];
            }
            for (int off = 32; off; off >>= 1) p += __shfl_xor(p, off, 64);
            sc_[k] = p;
        }
        float mx = -1e30f;
#pragma unroll
        for (int k = 0; k < 15; ++k) { sc_[k] = tanhf(sc_[k]); mx = fmaxf(mx, sc_[k]); }
        float Z = 0.0f, den = 0.0f, pk[15];
#pragma unroll
        for (int k = 0; k < 15; ++k) { pk[k] = __expf(sc_[k] - mx); Z += pk[k]; }
#pragma unroll
        for (int k = 0; k < 15; ++k) { pk[k] *= bw[k]; den += pk[k]; }
        den += 1e-6f * Z;                 // softmax*w / (sum + eps) exactly
        const float inv = 1.0f / den;
        unsigned short* bo = Abf + (long)m * K2 + 2048;
#pragma unroll
        for (int c = 0; c < 4; ++c) {
            const int e = lane + c * 64;
            float o = 0.0f;
            if (e < 200) {
#pragma unroll
                for (int k = 0; k < 15; ++k) o += pk[k] * pos_emb[(long)idx[k] * 200 + e];
                o *= inv;
            }
            bo[e] = f2bf(o);              // cols 200..255 get exact 0
        }
    }
}

// ============ GEMM2: dout(f32) = Abf[9216][3072] @ Wf^T ============
// 144x128 tile, 384 threads (2x3 waves), grid 512 = exactly 2 blocks/CU.
// Double-buffered staging, ONE barrier per K-step. nx = bid&7 -> Wf N-panel per XCD L2.
__global__ __launch_bounds__(384, 3) void k_gemm2(
    const unsigned short* __restrict__ Abf,
    const unsigned short* __restrict__ Wf,
    float* __restrict__ dout)
{
    __shared__ __align__(16) unsigned short shmA[2][144 * 64];   // 2 x 18,432 B
    __shared__ __align__(16) unsigned short shmB[2][128 * 64];   // 2 x 16,384 B
    const int t = threadIdx.x;
    const int lane = t & 63;
    const int w = t >> 6;                 // 0..5
    const int quad = lane >> 4;
    const int ln15 = lane & 15;
    const int x7 = ln15 & 7;
    const int nx = blockIdx.x & 7;        // 8 XCDs round-robin consecutive bids
    const int mx = blockIdx.x >> 3;       // 0..63
    const int m0 = mx * 144;
    const int n0 = nx * 128;
    const int lrow = lane >> 3;
    const int schunk = (lane & 7) ^ lrow;
    const int wm = (w % 3) * 48;
    const int wn = (w / 3) * 64;

    floatx4 acc[3][4] = {};

    // prologue: stage tile 0 into buf 0
#pragma unroll
    for (int i = 0; i < 6; ++i) {
        const int u = w + i * 6;          // 34 units: 0..17 A, 18..33 B
        if (u < 18)
            gl16(Abf + (long)(m0 + u * 8 + lrow) * K2 + schunk * 8, &shmA[0][u * 512]);
        else if (u < 34)
            gl16(Wf + (long)(n0 + (u - 18) * 8 + lrow) * K2 + schunk * 8,
                 &shmB[0][(u - 18) * 512]);
    }
    __syncthreads();

    int cur = 0;
    for (int kt = 0; kt < 48; ++kt) {
        if (kt < 47) {
            const int kbn = (kt + 1) * 64;
#pragma unroll
            for (int i = 0; i < 6; ++i) {
                const int u = w + i * 6;
                if (u < 18)
                    gl16(Abf + (long)(m0 + u * 8 + lrow) * K2 + kbn + schunk * 8,
                         &shmA[cur ^ 1][u * 512]);
                else if (u < 34)
                    gl16(Wf + (long)(n0 + (u - 18) * 8 + lrow) * K2 + kbn + schunk * 8,
                         &shmB[cur ^ 1][(u - 18) * 512]);
            }
        }
#pragma unroll
        for (int s = 0; s < 2; ++s) {
            const int g = s * 4 + quad;
            const int co = (g ^ x7) << 3;
            bf16x8 a[3], b[4];
#pragma unroll
            for (int i = 0; i < 3; ++i)
                a[i] = *(const bf16x8*)&shmA[cur][(wm + i * 16 + ln15) * 64 + co];
#pragma unroll
            for (int j = 0; j < 4; ++j)
                b[j] = *(const bf16x8*)&shmB[cur][(wn + j * 16 + ln15) * 64 + co];
#pragma unroll
            for (int i = 0; i < 3; ++i)
#pragma unroll
                for (int j = 0; j < 4; ++j)
                    acc[i][j] = __builtin_amdgcn_mfma_f32_16x16x32_bf16(a[i], b[j], acc[i][j], 0, 0, 0);
        }
        __syncthreads();
        cur ^= 1;
    }
#pragma unroll
    for (int i = 0; i < 3; ++i)
#pragma unroll
        for (int j = 0; j < 4; ++j) {
            const int row = m0 + wm + i * 16 + quad * 4;
            const int col = n0 + wn + j * 16 + ln15;
#pragma unroll
            for (int r = 0; r < 4; ++r)
                dout[(long)(row + r) * ES + col] = acc[i][j][r];
        }
}

// ============ bias + L2 normalize, IN-PLACE in d_out (f32) ============
__global__ __launch_bounds__(256) void k_norm(
    float* __restrict__ dout,
    const float* __restrict__ bias)
{
    __shared__ float red[4];
    const int m = blockIdx.x;
    const int t = threadIdx.x;
    float* f = dout + (long)m * ES + t * 4;
    float4 v = *(const float4*)f;
    const float4 bs = *(const float4*)(bias + t * 4);
    v.x += bs.x; v.y += bs.y; v.z += bs.z; v.w += bs.w;
    float ss = v.x * v.x + v.y * v.y + v.z * v.z + v.w * v.w;
    for (int off = 32; off; off >>= 1) ss += __shfl_xor(ss, off, 64);
    if ((t & 63) == 0) red[t >> 6] = ss;
    __syncthreads();
    const float total = red[0] + red[1] + red[2] + red[3];
    const float inv = 1.0f / (sqrtf(total) + 1e-8f);
    float4 o;
    o.x = v.x * inv; o.y = v.y * inv; o.z = v.z * inv; o.w = v.w * inv;
    *(float4*)f = o;
}

// ============ launch ============
extern "C" void kernel_launch(void* const* d_in, const int* in_sizes, int n_in,
                              void* d_out, int out_size, void* d_ws, size_t ws_size,
                              hipStream_t stream) {
    const float* images  = (const float*)d_in[0];
    const float* tag     = (const float*)d_in[1];
    const float* boxes   = (const float*)d_in[2];
    const float* pos_emb = (const float*)d_in[3];
    const float* attn_W  = (const float*)d_in[4];
    const float* fc_W    = (const float*)d_in[5];
    const float* fc_b    = (const float*)d_in[6];
    float* out = (float*)d_out;

    unsigned short* Abf = (unsigned short*)d_ws;            // 56,623,104 B
    unsigned short* Wf  = Abf + (size_t)M_TOT * K2;         //  6,291,456 B
    unsigned short* Wa  = Wf  + (size_t)ES * K2;            //  1,171,456 B
    // total workspace: 64,086,016 B

    k_prep_w    <<<1822, 256, 0, stream>>>(attn_W, fc_W, Wa, Wf);
    k_gemm1_attn<<<576, 384, 0, stream>>>(images, tag, Wa, boxes, pos_emb, Abf);
    k_gemm2     <<<512, 384, 0, stream>>>(Abf, Wf, out);
    k_norm      <<<M_TOT, 256, 0, stream>>>(out, fc_b);
}

// Round 4
// 316.020 us; speedup vs baseline: 1.3341x; 1.2592x over previous
//
#include <hip/hip_runtime.h>

// Pipeline (4 kernels):
//   k_prep       : grid-stride f32->bf16 conversion of ALL operands:
//                  Abf img/tag cols, Wf (remapped, gap zero), Wa (rows 200..207 zero)
//   k_gemm1_attn : region GEMM (Abf imgtag cols @ Wa^T) + fused attention,
//                  single-LDS-buffer, 2 barriers/K-step, gl16 staging, 4 blocks/CU
//   k_gemm2      : dout = Abf @ Wf^T, 128x128 tile, grid (72,8), single-buffer,
//                  2 barriers/K-step, gl16 staging, 4 blocks/CU
//   k_norm       : bias + L2 normalize in place
// Workspace (64,086,016 B): Abf[9216][3072] | Wf[1024][3072] | Wa[208][2816]
//
// LESSON (R3): dbuf+1-barrier halves blocks/CU and __syncthreads drains vmcnt(0)
// anyway -> strictly worse than small-LDS + 2 barriers + high TLP. Keep TLP.

#define M_TOT 9216
#define K1    2816
#define K2    3072
#define ES    1024

typedef __attribute__((ext_vector_type(8))) short bf16x8;
typedef __attribute__((ext_vector_type(4))) float floatx4;

static __device__ __forceinline__ unsigned short f2bf(float f) {
    unsigned int u = __float_as_uint(f);
    u += 0x7fffu + ((u >> 16) & 1u);   // RNE
    return (unsigned short)(u >> 16);
}

static __device__ __forceinline__ void cvt8(const float* __restrict__ g,
                                            unsigned short* __restrict__ d) {
    const float4 f0 = *(const float4*)g;
    const float4 f1 = *(const float4*)(g + 4);
    uint4 pk;
    pk.x = (unsigned)f2bf(f0.x) | ((unsigned)f2bf(f0.y) << 16);
    pk.y = (unsigned)f2bf(f0.z) | ((unsigned)f2bf(f0.w) << 16);
    pk.z = (unsigned)f2bf(f1.x) | ((unsigned)f2bf(f1.y) << 16);
    pk.w = (unsigned)f2bf(f1.z) | ((unsigned)f2bf(f1.w) << 16);
    *(uint4*)d = pk;
}

// async global->LDS, 16 B per lane; LDS dest must be wave-uniform base (+lane*16)
static __device__ __forceinline__ void gl16(const void* g, const void* l) {
    __builtin_amdgcn_global_load_lds(
        (const __attribute__((address_space(1))) unsigned int*)g,
        (__attribute__((address_space(3))) unsigned int*)(unsigned int)(unsigned long long)l,
        16, 0, 0);
}

// ============ prep: all f32 -> bf16 conversions, one chunk (8 elems) per thread ============
// chunks: [0, 3244032)            Abf img/tag  (9216 rows x 352 chunks)
//         [3244032, 3637248)      Wf           (1024 rows x 384 chunks)
//         [3637248, 3710464)      Wa           ( 208 rows x 352 chunks)
#define NC_ABF (9216 * 352)
#define NC_WF  (1024 * 384)
#define NC_WA  ( 208 * 352)
__global__ __launch_bounds__(256) void k_prep(
    const float* __restrict__ images,   // [9216][2048]
    const float* __restrict__ tag,      // [9216][768]
    const float* __restrict__ attn_W,   // [200][2816]
    const float* __restrict__ fc_W,     // [1024][3016]
    unsigned short* __restrict__ Abf,   // [9216][3072]
    unsigned short* __restrict__ Wa,    // [208][2816]
    unsigned short* __restrict__ Wf)    // [1024][3072]
{
    const int u = blockIdx.x * 256 + threadIdx.x;
    uint4 z; z.x = z.y = z.z = z.w = 0u;
    if (u < NC_ABF) {
        const int m = u / 352;
        const int c = u - m * 352;
        if (c < 256) cvt8(images + (long)m * 2048 + c * 8, Abf + (long)m * K2 + c * 8);
        else         cvt8(tag + (long)m * 768 + (c - 256) * 8,
                          Abf + (long)m * K2 + 2304 + (c - 256) * 8);
    } else if (u < NC_ABF + NC_WF) {
        const int v = u - NC_ABF;
        const int r = v / 384;
        const int dc = (v - r * 384) * 8;
        unsigned short* d = Wf + (long)r * K2 + dc;
        if (dc < 2248)      cvt8(fc_W + (long)r * 3016 + dc, d);        // img+box cols
        else if (dc < 2304) *(uint4*)d = z;                             // zero gap
        else                cvt8(fc_W + (long)r * 3016 + (dc - 56), d); // tag cols
    } else if (u < NC_ABF + NC_WF + NC_WA) {
        const int v = u - NC_ABF - NC_WF;
        const int r = v / 352;
        const int c = (v - r * 352) * 8;
        if (r < 200) cvt8(attn_W + (long)r * K1 + c, Wa + (long)r * K1 + c);
        else         *(uint4*)(Wa + (long)r * K1 + c) = z;
    }
}

// ============ GEMM1 (region = imgtag @ Wa^T) + fused attention ============
// grid 576 x 256 threads. Block: 16 rows x 208 cols. Single LDS buffer (28.7 KB)
// -> 4 blocks/CU resident; 2 barriers/K-step; gl16 + XOR chunk swizzle.
__global__ __launch_bounds__(256, 4) void k_gemm1_attn(
    const unsigned short* __restrict__ Abf,   // [9216][3072] (reads cols !2048..2303)
    const unsigned short* __restrict__ Wa,    // [208][2816]
    const float* __restrict__ boxes,          // [9216][30]
    const float* __restrict__ pos_emb,        // [257][200]
    unsigned short* __restrict__ AbfBox)      // = Abf; writes cols 2048..2303
{
    __shared__ __align__(16) unsigned short lds[14336];   // 28,672 B
    unsigned short* ldsA = lds;          // [16][64] swizzled
    unsigned short* ldsB = lds + 1024;   // [208][64] swizzled
    float* ldsR = (float*)lds;           // [16][212] region f32 (reused after K-loop)

    const int t = threadIdx.x;
    const int lane = t & 63;
    const int w = t >> 6;
    const int quad = lane >> 4;
    const int ln15 = lane & 15;
    const int x7 = ln15 & 7;
    const int m0 = blockIdx.x * 16;
    const int lrow = lane >> 3;                 // LDS row within 8-row unit
    const int schunk = (lane & 7) ^ lrow;       // inverse-swizzled source 16B chunk
    const int nj = (w == 0) ? 4 : 3;            // wave0: j=0,4,8,12; else w,w+4,w+8

    floatx4 acc[4] = {};

    for (int kt = 0; kt < 44; ++kt) {
        const int kb = kt * 64;
        const int acol = kb + ((kb >= 2048) ? 256 : 0);   // skip boxfeat gap in Abf
#pragma unroll
        for (int i = 0; i < 7; ++i) {
            const int u = w + i * 4;            // 28 units: 0..25 = B rows, 26..27 = A
            if (u < 26) {
                const int r = u * 8 + lrow;     // 0..207
                gl16(Wa + (long)r * K1 + kb + schunk * 8, ldsB + u * 512);
            } else {
                const int r = (u - 26) * 8 + lrow;  // 0..15
                gl16(Abf + (long)(m0 + r) * K2 + acol + schunk * 8,
                     ldsA + (u - 26) * 512);
            }
        }
        __syncthreads();
#pragma unroll
        for (int s = 0; s < 2; ++s) {
            const int g = s * 4 + quad;
            const int co = (g ^ x7) << 3;       // swizzled read chunk
            const bf16x8 a = *(const bf16x8*)&ldsA[ln15 * 64 + co];
#pragma unroll
            for (int jj = 0; jj < 4; ++jj) {
                if (jj < nj) {
                    const int j = w + jj * 4;
                    const bf16x8 b = *(const bf16x8*)&ldsB[(j * 16 + ln15) * 64 + co];
                    acc[jj] = __builtin_amdgcn_mfma_f32_16x16x32_bf16(a, b, acc[jj], 0, 0, 0);
                }
            }
        }
        __syncthreads();
    }

    // region tile -> LDS f32 [16][212] (C layout: row = quad*4+reg, col = j*16+ln15)
#pragma unroll
    for (int jj = 0; jj < 4; ++jj) {
        if (jj < nj) {
            const int j = w + jj * 4;
#pragma unroll
            for (int r = 0; r < 4; ++r)
                ldsR[(quad * 4 + r) * 212 + j * 16 + ln15] = acc[jj][r];
        }
    }
    __syncthreads();

    // attention: wave w handles rows w*4 .. w*4+3
    for (int rr = 0; rr < 4; ++rr) {
        const int ml = w * 4 + rr;
        const int m = m0 + ml;
        float rv[4];
#pragma unroll
        for (int c = 0; c < 4; ++c) {
            const int e = lane + c * 64;
            rv[c] = (e < 200) ? ldsR[ml * 212 + e] : 0.0f;
        }
        const float* bx = boxes + (long)m * 30;
        int idx[15]; float bw[15], sc_[15];
#pragma unroll
        for (int k = 0; k < 15; ++k) {
            int ii = (int)bx[k];
            idx[k] = (ii < 0) ? 0 : (ii > 256 ? 256 : ii);
            bw[k] = bx[15 + k];
        }
#pragma unroll
        for (int k = 0; k < 15; ++k) {
            const float* em = pos_emb + (long)idx[k] * 200;
            float p = 0.0f;
#pragma unroll
            for (int c = 0; c < 4; ++c) {
                const int e = lane + c * 64;
                if (e < 200) p += rv[c] * em[e];
            }
            for (int off = 32; off; off >>= 1) p += __shfl_xor(p, off, 64);
            sc_[k] = p;
        }
        float mx = -1e30f;
#pragma unroll
        for (int k = 0; k < 15; ++k) { sc_[k] = tanhf(sc_[k]); mx = fmaxf(mx, sc_[k]); }
        float Z = 0.0f, den = 0.0f, pk[15];
#pragma unroll
        for (int k = 0; k < 15; ++k) { pk[k] = __expf(sc_[k] - mx); Z += pk[k]; }
#pragma unroll
        for (int k = 0; k < 15; ++k) { pk[k] *= bw[k]; den += pk[k]; }
        den += 1e-6f * Z;                 // softmax*w / (sum + eps) exactly
        const float inv = 1.0f / den;
        unsigned short* bo = AbfBox + (long)m * K2 + 2048;
#pragma unroll
        for (int c = 0; c < 4; ++c) {
            const int e = lane + c * 64;
            float o = 0.0f;
            if (e < 200) {
#pragma unroll
                for (int k = 0; k < 15; ++k) o += pk[k] * pos_emb[(long)idx[k] * 200 + e];
                o *= inv;
            }
            bo[e] = f2bf(o);              // cols 200..255 get exact 0
        }
    }
}

// ============ GEMM2: dout(f32) = Abf[9216][3072] @ Wf^T ============
// grid (72,8), 128x128 tile, single-buffer (32.7 KB) -> 4 blocks/CU resident.
__global__ __launch_bounds__(256, 4) void k_gemm2(
    const unsigned short* __restrict__ Abf,
    const unsigned short* __restrict__ Wf,
    float* __restrict__ dout)
{
    __shared__ __align__(16) unsigned short ldsA[128 * 64];
    __shared__ __align__(16) unsigned short ldsB[128 * 64];
    const int t = threadIdx.x;
    const int lane = t & 63;
    const int w = t >> 6;
    const int quad = lane >> 4;
    const int ln15 = lane & 15;
    const int x7 = ln15 & 7;
    const int m0 = blockIdx.x * 128;
    const int n0 = blockIdx.y * 128;
    const int lrow = lane >> 3;
    const int schunk = (lane & 7) ^ lrow;
    const int wm = (w & 1) * 64;
    const int wn = (w >> 1) * 64;

    floatx4 acc[4][4] = {};

    for (int kt = 0; kt < 48; ++kt) {
        const int kb = kt * 64;
#pragma unroll
        for (int i = 0; i < 4; ++i) {
            const int u = w * 4 + i;            // 0..15: 8-row groups
            const int r = u * 8 + lrow;         // 0..127
            gl16(Abf + (long)(m0 + r) * K2 + kb + schunk * 8, ldsA + u * 512);
            gl16(Wf  + (long)(n0 + r) * K2 + kb + schunk * 8, ldsB + u * 512);
        }
        __syncthreads();
#pragma unroll
        for (int s = 0; s < 2; ++s) {
            const int g = s * 4 + quad;
            const int co = (g ^ x7) << 3;
            bf16x8 a[4], b[4];
#pragma unroll
            for (int i = 0; i < 4; ++i)
                a[i] = *(const bf16x8*)&ldsA[(wm + i * 16 + ln15) * 64 + co];
#pragma unroll
            for (int j = 0; j < 4; ++j)
                b[j] = *(const bf16x8*)&ldsB[(wn + j * 16 + ln15) * 64 + co];
#pragma unroll
            for (int i = 0; i < 4; ++i)
#pragma unroll
                for (int j = 0; j < 4; ++j)
                    acc[i][j] = __builtin_amdgcn_mfma_f32_16x16x32_bf16(a[i], b[j], acc[i][j], 0, 0, 0);
        }
        __syncthreads();
    }
#pragma unroll
    for (int i = 0; i < 4; ++i)
#pragma unroll
        for (int j = 0; j < 4; ++j) {
            const int row = m0 + wm + i * 16 + quad * 4;
            const int col = n0 + wn + j * 16 + ln15;
#pragma unroll
            for (int r = 0; r < 4; ++r)
                dout[(long)(row + r) * ES + col] = acc[i][j][r];
        }
}

// ============ bias + L2 normalize, IN-PLACE in d_out (f32) ============
__global__ __launch_bounds__(256) void k_norm(
    float* __restrict__ dout,
    const float* __restrict__ bias)
{
    __shared__ float red[4];
    const int m = blockIdx.x;
    const int t = threadIdx.x;
    float* f = dout + (long)m * ES + t * 4;
    float4 v = *(const float4*)f;
    const float4 bs = *(const float4*)(bias + t * 4);
    v.x += bs.x; v.y += bs.y; v.z += bs.z; v.w += bs.w;
    float ss = v.x * v.x + v.y * v.y + v.z * v.z + v.w * v.w;
    for (int off = 32; off; off >>= 1) ss += __shfl_xor(ss, off, 64);
    if ((t & 63) == 0) red[t >> 6] = ss;
    __syncthreads();
    const float total = red[0] + red[1] + red[2] + red[3];
    const float inv = 1.0f / (sqrtf(total) + 1e-8f);
    float4 o;
    o.x = v.x * inv; o.y = v.y * inv; o.z = v.z * inv; o.w = v.w * inv;
    *(float4*)f = o;
}

// ============ launch ============
extern "C" void kernel_launch(void* const* d_in, const int* in_sizes, int n_in,
                              void* d_out, int out_size, void* d_ws, size_t ws_size,
                              hipStream_t stream) {
    const float* images  = (const float*)d_in[0];
    const float* tag     = (const float*)d_in[1];
    const float* boxes   = (const float*)d_in[2];
    const float* pos_emb = (const float*)d_in[3];
    const float* attn_W  = (const float*)d_in[4];
    const float* fc_W    = (const float*)d_in[5];
    const float* fc_b    = (const float*)d_in[6];
    float* out = (float*)d_out;

    unsigned short* Abf = (unsigned short*)d_ws;            // 56,623,104 B
    unsigned short* Wf  = Abf + (size_t)M_TOT * K2;         //  6,291,456 B
    unsigned short* Wa  = Wf  + (size_t)ES * K2;            //  1,171,456 B
    // total workspace: 64,086,016 B

    const int prep_blocks = (NC_ABF + NC_WF + NC_WA + 255) / 256;   // 14,494
    k_prep      <<<prep_blocks, 256, 0, stream>>>(images, tag, attn_W, fc_W, Abf, Wa, Wf);
    k_gemm1_attn<<<576, 256, 0, stream>>>(Abf, Wa, boxes, pos_emb, Abf);
    k_gemm2     <<<dim3(72, 8), 256, 0, stream>>>(Abf, Wf, out);
    k_norm      <<<M_TOT, 256, 0, stream>>>(out, fc_b);
}